// Round 9
// baseline (147.595 us; speedup 1.0000x reference)
//
#include <hip/hip_runtime.h>
#include <math.h>

#define N_    1024
#define H_    16
#define E_    16384
#define SCALE 0.125f

typedef unsigned short u16;
typedef unsigned int   u32;
typedef short  short8v __attribute__((ext_vector_type(8)));
typedef float  f32x4   __attribute__((ext_vector_type(4)));
typedef u16    u16x4   __attribute__((ext_vector_type(4)));
typedef u16    u16x8   __attribute__((ext_vector_type(8)));

__device__ __forceinline__ u16 f2bf(float f) {
    union { float f; unsigned u; } v; v.f = f;
    unsigned r = v.u + 0x7fffu + ((v.u >> 16) & 1u);
    return (u16)(r >> 16);
}
__device__ __forceinline__ float bf2f(u16 u) {
    union { unsigned u; float f; } v; v.u = (u32)u << 16; return v.f;
}

// ---------------------------------------------------------------
// staging: global(bf16, row-major, ld=ldr) -> LDS tile [rows][64]
// XOR slot swizzle applied on the GLOBAL source (linear LDS dest).
// ---------------------------------------------------------------
template<int U64>
__device__ __forceinline__ void stage_bt(const u16* __restrict__ g, int ldr,
                                         u16* s, int tid)
{
    const int l = tid & 63, w = tid >> 6;
    for (int c = w; c < U64; c += 4) {
        int o16 = (c << 6) + l;
        int row = o16 >> 3;
        int ss  = (o16 & 7) ^ (row & 7);
        const u16* gp = g + (size_t)row * ldr + (ss << 3);
        u16* lp = s + (c << 9);
        __builtin_amdgcn_global_load_lds(
            (const __attribute__((address_space(1))) void*)gp,
            (__attribute__((address_space(3))) void*)lp, 16, 0, 0);
    }
}

__device__ __forceinline__ short8v frag_read(const u16* s, int row, int slot) {
    return *(const short8v*)(s + row * 64 + ((slot ^ (row & 7)) << 3));
}

// ---------------------------------------------------------------
// bf16 GEMM-BT core: block tile 128 x NT, 4 waves (2x2), BK=64.
// ---------------------------------------------------------------
template<int NT>
__device__ __forceinline__ void gemm_bt_core(
    const u16* __restrict__ At, int lda,
    const u16* __restrict__ Bt, int ldb,
    int K, u16* As, u16* Bs, f32x4 (&acc)[4][NT/32], int tid)
{
    const int l  = tid & 63;
    const int wm = tid >> 7, wn = (tid >> 6) & 1;
    const int lr = l & 15,   lk = l >> 4;
    for (int k0 = 0; k0 < K; k0 += 64) {
        if (k0) __syncthreads();
        stage_bt<16>(At + k0, lda, As, tid);
        stage_bt<NT/8>(Bt + k0, ldb, Bs, tid);
        __syncthreads();
        #pragma unroll
        for (int s = 0; s < 2; ++s) {
            short8v af[4], bfv[NT/32];
            #pragma unroll
            for (int i = 0; i < 4; ++i)
                af[i] = frag_read(As, wm*64 + i*16 + lr, s*4 + lk);
            #pragma unroll
            for (int j = 0; j < NT/32; ++j)
                bfv[j] = frag_read(Bs, wn*(NT/2) + j*16 + lr, s*4 + lk);
            #pragma unroll
            for (int i = 0; i < 4; ++i)
                #pragma unroll
                for (int j = 0; j < NT/32; ++j)
                    asm("v_mfma_f32_16x16x32_bf16 %0, %1, %2, %0"
                        : "+v"(acc[i][j]) : "v"(af[i]), "v"(bfv[j]));
        }
    }
    __syncthreads();
}

// ---------------------------------------------------------------
// converts
// ---------------------------------------------------------------
__global__ __launch_bounds__(256) void conv_x(const float* __restrict__ X,
                                              u16* __restrict__ Xb)
{
    size_t i = (size_t)blockIdx.x * 256 + threadIdx.x;
    float4 a = ((const float4*)X)[2*i], b = ((const float4*)X)[2*i + 1];
    u16x8 o;
    o[0]=f2bf(a.x); o[1]=f2bf(a.y); o[2]=f2bf(a.z); o[3]=f2bf(a.w);
    o[4]=f2bf(b.x); o[5]=f2bf(b.y); o[6]=f2bf(b.z); o[7]=f2bf(b.w);
    *(u16x8*)&Xb[8*i] = o;
}

__global__ __launch_bounds__(256) void conv_wt(
    const float* __restrict__ Wq, const float* __restrict__ Wk,
    const float* __restrict__ Wv, const float* __restrict__ Wo,
    u16* __restrict__ Wt)
{
    __shared__ u16 tile[64][65];
    const int t = threadIdx.x;
    const int n0 = blockIdx.x*64, k0 = blockIdx.y*64, mz = blockIdx.z;
    const float* W = mz==0 ? Wq : mz==1 ? Wk : mz==2 ? Wv : Wo;
    u16* Wd = Wt + (size_t)mz * 1024 * 1024;
    #pragma unroll
    for (int p = 0; p < 4; ++p) {
        int r = p*16 + (t>>4), c = (t&15)*4;
        float4 v = *(const float4*)&W[(size_t)(k0+r)*1024 + n0 + c];
        tile[c+0][r]=f2bf(v.x); tile[c+1][r]=f2bf(v.y);
        tile[c+2][r]=f2bf(v.z); tile[c+3][r]=f2bf(v.w);
    }
    __syncthreads();
    #pragma unroll
    for (int p = 0; p < 4; ++p) {
        int nr = p*16 + (t>>4), kc = (t&15)*4;
        u16x4 o = { tile[nr][kc], tile[nr][kc+1], tile[nr][kc+2], tile[nr][kc+3] };
        *(u16x4*)&Wd[(size_t)(n0+nr)*1024 + k0 + kc] = o;
    }
}

__global__ __launch_bounds__(256) void transpose_v(const u16* __restrict__ Vb,
                                                   u16* __restrict__ Vt)
{
    __shared__ u16 tile[64][65];
    const int t = threadIdx.x;
    const int c0 = blockIdx.x*64, r0 = blockIdx.y*64;
    #pragma unroll
    for (int p = 0; p < 4; ++p) {
        int r = p*16 + (t>>4), c = (t&15)*4;
        u16x4 v = *(const u16x4*)&Vb[(size_t)(r0+r)*1024 + c0 + c];
        tile[c+0][r]=v[0]; tile[c+1][r]=v[1]; tile[c+2][r]=v[2]; tile[c+3][r]=v[3];
    }
    __syncthreads();
    #pragma unroll
    for (int p = 0; p < 4; ++p) {
        int cr = p*16 + (t>>4), rc = (t&15)*4;
        u16x4 o = { tile[cr][rc], tile[cr][rc+1], tile[cr][rc+2], tile[cr][rc+3] };
        *(u16x4*)&Vt[(size_t)(c0+cr)*1024 + r0 + rc] = o;
    }
}

// ---------------------------------------------------------------
// C[e][l][h] = dot(edge_feat[e], edge_weight[l][h]) ; row E = 0
// Output bf16 (halves gather bytes; C fits in per-XCD L2).
// ---------------------------------------------------------------
__global__ __launch_bounds__(256) void edge_pre_kernel(
    const float* __restrict__ EF, const float* __restrict__ EW, u16* __restrict__ C)
{
    __shared__ float ews[64][66];
    __shared__ float ef[16][64];
    const int t = threadIdx.x;
    const int e0 = blockIdx.x * 16;
    #pragma unroll
    for (int i = 0; i < 16; ++i) {
        int idx = t + i * 256;
        ews[idx >> 6][idx & 63] = EW[idx];
    }
    #pragma unroll
    for (int i = 0; i < 4; ++i) {
        int idx = t + i * 256;
        int r = idx >> 6, d = idx & 63;
        int e = e0 + r;
        ef[r][d] = (e < E_) ? EF[(size_t)e * 64 + d] : 0.f;
    }
    __syncthreads();
    const int lh = t & 63;
    const int rb = t >> 6;
    #pragma unroll
    for (int j = 0; j < 4; ++j) {
        int r = rb * 4 + j;
        int e = e0 + r;
        if (e > E_) continue;
        float acc = 0.f;
        if (e < E_) {
            #pragma unroll
            for (int d = 0; d < 64; ++d) acc += ef[r][d] * ews[lh][d];
        }
        C[(size_t)e * 64 + lh] = f2bf(acc);
    }
}

// ---------------------------------------------------------------
// GEMM kernels
// ---------------------------------------------------------------
__global__ __launch_bounds__(256) void qkv_gemm(
    const u16* __restrict__ Xb, const u16* __restrict__ Wt,
    const float* __restrict__ bq, const float* __restrict__ bk,
    const float* __restrict__ bv,
    u16* __restrict__ Qb, u16* __restrict__ Kb, u16* __restrict__ Vb)
{
    __shared__ u16 As[128*64], Bs[128*64];
    const int tid = threadIdx.x;
    const int col0 = blockIdx.x * 128, row0 = blockIdx.y * 128;
    f32x4 acc[4][4] = {};
    gemm_bt_core<128>(Xb + (size_t)row0*1024, 1024,
                      Wt + (size_t)col0*1024, 1024, 1024, As, Bs, acc, tid);
    const int l = tid & 63, wm = tid>>7, wn = (tid>>6)&1, lr = l&15, lk = l>>4;
    const int sel = col0 >> 10;
    const float* bias = sel==0 ? bq : sel==1 ? bk : bv;
    u16* O = sel==0 ? Qb : sel==1 ? Kb : Vb;
    const int cbase = col0 & 1023;
    #pragma unroll
    for (int j = 0; j < 4; ++j) {
        int cc = cbase + wn*64 + j*16 + lr;
        float bb = bias[cc];
        #pragma unroll
        for (int i = 0; i < 4; ++i) {
            int rg = row0 + wm*64 + i*16 + lk*4;
            #pragma unroll
            for (int r = 0; r < 4; ++r)
                O[(size_t)(rg + r)*1024 + cc] = f2bf(acc[i][j][r] + bb);
        }
    }
}

__global__ __launch_bounds__(256) void qk_gemm(
    const u16* __restrict__ Qb, const u16* __restrict__ Kb, float* __restrict__ S)
{
    __shared__ u16 As[128*64], Bs[128*64];
    const int tid = threadIdx.x;
    const int col0 = blockIdx.x*128, row0 = blockIdx.y*128, h = blockIdx.z;
    f32x4 acc[4][4] = {};
    gemm_bt_core<128>(Qb + (size_t)row0*1024 + h*64, 1024,
                      Kb + (size_t)col0*1024 + h*64, 1024, 64, As, Bs, acc, tid);
    const int l = tid & 63, wm = tid>>7, wn = (tid>>6)&1, lr = l&15, lk = l>>4;
    float* So = S + ((size_t)h << 20);
    #pragma unroll
    for (int j = 0; j < 4; ++j) {
        int cg = col0 + wn*64 + j*16 + lr;
        #pragma unroll
        for (int i = 0; i < 4; ++i) {
            int rg = row0 + wm*64 + i*16 + lk*4;
            #pragma unroll
            for (int r = 0; r < 4; ++r)
                So[(size_t)(rg + r)*1024 + cg] = acc[i][j][r] * SCALE;
        }
    }
}

__global__ __launch_bounds__(256) void pv_gemm(
    const u16* __restrict__ P, const u16* __restrict__ Vt, u16* __restrict__ AO)
{
    __shared__ u16 As[128*64], Bs[64*64];
    const int tid = threadIdx.x;
    const int row0 = blockIdx.x * 128, h = blockIdx.y;
    f32x4 acc[4][2] = {};
    gemm_bt_core<64>(P + ((size_t)((h<<10) + row0)) * 2048, 2048,
                     Vt + (size_t)h*64*1024, 1024, 1024, As, Bs, acc, tid);
    const int l = tid & 63, wm = tid>>7, wn = (tid>>6)&1, lr = l&15, lk = l>>4;
    #pragma unroll
    for (int j = 0; j < 2; ++j) {
        int col = h*64 + wn*32 + j*16 + lr;
        #pragma unroll
        for (int i = 0; i < 4; ++i) {
            int rg = row0 + wm*64 + i*16 + lk*4;
            #pragma unroll
            for (int r = 0; r < 4; ++r)
                AO[(size_t)(rg + r)*1024 + col] = f2bf(acc[i][j][r]);
        }
    }
}

__global__ __launch_bounds__(256) void out_gemm(
    const u16* __restrict__ AO, const u16* __restrict__ Wot,
    const float* __restrict__ bo, float* __restrict__ out)
{
    __shared__ u16 As[128*64], Bs[128*64];
    const int tid = threadIdx.x;
    const int col0 = blockIdx.x * 128, row0 = blockIdx.y * 128;
    f32x4 acc[4][4] = {};
    gemm_bt_core<128>(AO + (size_t)row0*1024, 1024,
                      Wot + (size_t)col0*1024, 1024, 1024, As, Bs, acc, tid);
    const int l = tid & 63, wm = tid>>7, wn = (tid>>6)&1, lr = l&15, lk = l>>4;
    #pragma unroll
    for (int j = 0; j < 4; ++j) {
        int cg = col0 + wn*64 + j*16 + lr;
        float bb = bo[cg];
        #pragma unroll
        for (int i = 0; i < 4; ++i) {
            int rg = row0 + wm*64 + i*16 + lk*4;
            #pragma unroll
            for (int r = 0; r < 4; ++r)
                out[(size_t)(rg + r)*1024 + cg] = acc[i][j][r] + bb;
        }
    }
}

// ---------------------------------------------------------------
// bias (spatial + edge enc) + mask + softmax; S is fp32 [h][n][m].
// Exact R6 semantics (int sdl LDS, stbl LDS, fp32 bias LDS); the
// only change vs R6: path indices sp are kept in two int4 REGISTERS
// per thread (gather phase m-set == thread's own m's), removing the
// 16KB sp LDS arrays -> 36.6KB LDS -> 4 blocks/CU.
// bf16 probs packed into the first 1024 u16 of each fp32 row.
// ---------------------------------------------------------------
__global__ __launch_bounds__(512) void bias_softmax7(
    const int* __restrict__ SD, const int* __restrict__ SP,
    const u16* __restrict__ C, const float* __restrict__ STBL,
    float* __restrict__ S)
{
    __shared__ int   sdl[1024];
    __shared__ float stbl[80];
    __shared__ float bias[8][1024];
    const int t = threadIdx.x;
    const int n = blockIdx.x;
    const int w = t >> 6, lane = t & 63;
    #pragma unroll
    for (int k = 0; k < 2; ++k) {
        int m = t + k*512;
        sdl[m] = SD[(size_t)n*1024 + m];
    }
    const int4 v0 = *(const int4*)&SP[((size_t)n*1024 + t)*4];
    const int4 v1 = *(const int4*)&SP[((size_t)n*1024 + t + 512)*4];
    if (t < 80) stbl[t] = STBL[t];

    // T14 async-split: issue both head-row loads now; consume after gather.
    float2 pre0[8], pre1[8];
    {
        const float* sr0 = S + (((size_t)w << 10) + n) * 1024;
        const float* sr1 = S + (((size_t)(w + 8) << 10) + n) * 1024;
        #pragma unroll
        for (int j = 0; j < 8; ++j) pre0[j] = *(const float2*)&sr0[lane*2 + j*128];
        #pragma unroll
        for (int j = 0; j < 8; ++j) pre1[j] = *(const float2*)&sr1[lane*2 + j*128];
    }
    __syncthreads();

    #pragma unroll
    for (int hc = 0; hc < 16; hc += 8) {
        if (hc) __syncthreads();
        #pragma unroll
        for (int k = 0; k < 2; ++k) {
            int m   = t + k*512;
            int4 e4 = k ? v1 : v0;
            int sdv = sdl[m];
            int cl  = sdv > 4 ? 4 : (sdv < 0 ? 0 : sdv);
            float4 b0 = *(const float4*)&stbl[cl*16 + hc];
            float4 b1 = *(const float4*)&stbl[cl*16 + hc + 4];
            u16x8 A0 = *(const u16x8*)&C[(size_t)e4.x*64 +  0 + hc];
            u16x8 D0 = *(const u16x8*)&C[(size_t)e4.y*64 + 16 + hc];
            u16x8 F0 = *(const u16x8*)&C[(size_t)e4.z*64 + 32 + hc];
            u16x8 G0 = *(const u16x8*)&C[(size_t)e4.w*64 + 48 + hc];
            bias[0][m] = b0.x + bf2f(A0[0]) + bf2f(D0[0]) + bf2f(F0[0]) + bf2f(G0[0]);
            bias[1][m] = b0.y + bf2f(A0[1]) + bf2f(D0[1]) + bf2f(F0[1]) + bf2f(G0[1]);
            bias[2][m] = b0.z + bf2f(A0[2]) + bf2f(D0[2]) + bf2f(F0[2]) + bf2f(G0[2]);
            bias[3][m] = b0.w + bf2f(A0[3]) + bf2f(D0[3]) + bf2f(F0[3]) + bf2f(G0[3]);
            bias[4][m] = b1.x + bf2f(A0[4]) + bf2f(D0[4]) + bf2f(F0[4]) + bf2f(G0[4]);
            bias[5][m] = b1.y + bf2f(A0[5]) + bf2f(D0[5]) + bf2f(F0[5]) + bf2f(G0[5]);
            bias[6][m] = b1.z + bf2f(A0[6]) + bf2f(D0[6]) + bf2f(F0[6]) + bf2f(G0[6]);
            bias[7][m] = b1.w + bf2f(A0[7]) + bf2f(D0[7]) + bf2f(F0[7]) + bf2f(G0[7]);
        }
        __syncthreads();
        const int h = hc + w;
        float* srow = S + (((size_t)h << 10) + n) * 1024;
        float v[16];
        float lmax = -INFINITY;
        #pragma unroll
        for (int j = 0; j < 8; ++j) {
            int m = lane*2 + j*128;
            float2 sv = hc ? pre1[j] : pre0[j];
            float2 bb = *(const float2*)&bias[w][m];
            int2 sd2 = *(const int2*)&sdl[m];
            float x0 = (sd2.x <= 0) ? -INFINITY : sv.x + bb.x;
            float x1 = (sd2.y <= 0) ? -INFINITY : sv.y + bb.y;
            v[2*j] = x0; v[2*j+1] = x1;
            lmax = fmaxf(lmax, fmaxf(x0, x1));
        }
        #pragma unroll
        for (int o = 32; o; o >>= 1) lmax = fmaxf(lmax, __shfl_xor(lmax, o));
        float lsum = 0.f;
        #pragma unroll
        for (int j = 0; j < 16; ++j) { v[j] = __expf(v[j] - lmax); lsum += v[j]; }
        #pragma unroll
        for (int o = 32; o; o >>= 1) lsum += __shfl_xor(lsum, o);
        float inv = 1.f / lsum;
        u16* prow = (u16*)srow;
        #pragma unroll
        for (int j = 0; j < 8; ++j) {
            int m = lane*2 + j*128;
            u32 pk = ((u32)f2bf(v[2*j+1] * inv) << 16) | f2bf(v[2*j] * inv);
            *(u32*)&prow[m] = pk;
        }
    }
}

// ---------------------------------------------------------------
extern "C" void kernel_launch(void* const* d_in, const int* in_sizes, int n_in,
                              void* d_out, int out_size, void* d_ws, size_t ws_size,
                              hipStream_t stream)
{
    const float* node_feat = (const float*)d_in[0];
    const float* edge_feat = (const float*)d_in[1];
    const int*   sd        = (const int*)d_in[3];
    const int*   sp        = (const int*)d_in[4];
    const float* Wq = (const float*)d_in[6];
    const float* bq = (const float*)d_in[7];
    const float* Wk = (const float*)d_in[8];
    const float* bk = (const float*)d_in[9];
    const float* Wv = (const float*)d_in[10];
    const float* bv = (const float*)d_in[11];
    const float* Wo = (const float*)d_in[12];
    const float* bo = (const float*)d_in[13];
    const float* spatial = (const float*)d_in[14];
    const float* ew      = (const float*)d_in[15];
    float* out = (float*)d_out;

    char* base = (char*)d_ws;
    u16*   Xb = (u16*)(base);                           // 2MB (later Vt)
    u16*   Qb = (u16*)(base + ((size_t)2 << 20));       // 2MB (later attnout)
    u16*   Kb = (u16*)(base + ((size_t)4 << 20));       // 2MB
    u16*   Vb = (u16*)(base + ((size_t)6 << 20));       // 2MB
    u16*   Wt = (u16*)(base + ((size_t)8 << 20));       // 8MB
    u16*   C  = (u16*)(base + ((size_t)16 << 20));      // 2,097,280 B (bf16)
    float* S  = (float*)(base + ((size_t)19 << 20));    // 64MB fp32
    u16*   Vt = Xb;   // alias: Xb dead after qkv_gemm
    u16*   AO = Qb;   // alias: Qb dead after qk_gemm

    conv_x<<<512, 256, 0, stream>>>(node_feat, Xb);
    conv_wt<<<dim3(16,16,4), 256, 0, stream>>>(Wq, Wk, Wv, Wo, Wt);
    edge_pre_kernel<<<dim3(E_/16 + 1), 256, 0, stream>>>(edge_feat, ew, C);
    qkv_gemm<<<dim3(24,8), 256, 0, stream>>>(Xb, Wt, bq, bk, bv, Qb, Kb, Vb);
    transpose_v<<<dim3(16,16), 256, 0, stream>>>(Vb, Vt);
    qk_gemm<<<dim3(8,8,16), 256, 0, stream>>>(Qb, Kb, S);
    bias_softmax7<<<dim3(1024), 512, 0, stream>>>(sd, sp, C, spatial, S);
    pv_gemm<<<dim3(8,16), 256, 0, stream>>>((const u16*)S, Vt, AO);
    out_gemm<<<dim3(8,8), 256, 0, stream>>>(AO, Wt + (size_t)3*1024*1024, bo, out);
}

// Round 10
// 128.004 us; speedup vs baseline: 1.1530x; 1.1530x over previous
//
#include <hip/hip_runtime.h>
#include <math.h>

#define N_    1024
#define H_    16
#define E_    16384
#define SCALE 0.125f

typedef unsigned short u16;
typedef unsigned int   u32;
typedef short  short8v __attribute__((ext_vector_type(8)));
typedef float  f32x4   __attribute__((ext_vector_type(4)));
typedef u16    u16x4   __attribute__((ext_vector_type(4)));
typedef u16    u16x8   __attribute__((ext_vector_type(8)));

__device__ __forceinline__ u16 f2bf(float f) {
    union { float f; unsigned u; } v; v.f = f;
    unsigned r = v.u + 0x7fffu + ((v.u >> 16) & 1u);
    return (u16)(r >> 16);
}
__device__ __forceinline__ float bf2f(u16 u) {
    union { unsigned u; float f; } v; v.u = (u32)u << 16; return v.f;
}

// ---------------------------------------------------------------
// staging: global(bf16, row-major, ld=ldr) -> LDS tile [rows][64]
// XOR slot swizzle applied on the GLOBAL source (linear LDS dest).
// ---------------------------------------------------------------
template<int U64>
__device__ __forceinline__ void stage_bt(const u16* __restrict__ g, int ldr,
                                         u16* s, int tid)
{
    const int l = tid & 63, w = tid >> 6;
    for (int c = w; c < U64; c += 4) {
        int o16 = (c << 6) + l;
        int row = o16 >> 3;
        int ss  = (o16 & 7) ^ (row & 7);
        const u16* gp = g + (size_t)row * ldr + (ss << 3);
        u16* lp = s + (c << 9);
        __builtin_amdgcn_global_load_lds(
            (const __attribute__((address_space(1))) void*)gp,
            (__attribute__((address_space(3))) void*)lp, 16, 0, 0);
    }
}

__device__ __forceinline__ short8v frag_read(const u16* s, int row, int slot) {
    return *(const short8v*)(s + row * 64 + ((slot ^ (row & 7)) << 3));
}

// ---------------------------------------------------------------
// bf16 GEMM-BT core: block tile MT x NT, 4 waves (2x2), BK=64.
// Per-element accumulation order identical for all MT/NT.
// ---------------------------------------------------------------
template<int MT, int NT>
__device__ __forceinline__ void gemm_bt_core(
    const u16* __restrict__ At, int lda,
    const u16* __restrict__ Bt, int ldb,
    int K, u16* As, u16* Bs, f32x4 (&acc)[MT/32][NT/32], int tid)
{
    const int l  = tid & 63;
    const int wm = tid >> 7, wn = (tid >> 6) & 1;
    const int lr = l & 15,   lk = l >> 4;
    for (int k0 = 0; k0 < K; k0 += 64) {
        if (k0) __syncthreads();
        stage_bt<MT/8>(At + k0, lda, As, tid);
        stage_bt<NT/8>(Bt + k0, ldb, Bs, tid);
        __syncthreads();
        #pragma unroll
        for (int s = 0; s < 2; ++s) {
            short8v af[MT/32], bfv[NT/32];
            #pragma unroll
            for (int i = 0; i < MT/32; ++i)
                af[i] = frag_read(As, wm*(MT/2) + i*16 + lr, s*4 + lk);
            #pragma unroll
            for (int j = 0; j < NT/32; ++j)
                bfv[j] = frag_read(Bs, wn*(NT/2) + j*16 + lr, s*4 + lk);
            #pragma unroll
            for (int i = 0; i < MT/32; ++i)
                #pragma unroll
                for (int j = 0; j < NT/32; ++j)
                    asm("v_mfma_f32_16x16x32_bf16 %0, %1, %2, %0"
                        : "+v"(acc[i][j]) : "v"(af[i]), "v"(bfv[j]));
        }
    }
    __syncthreads();
}

// ---------------------------------------------------------------
// converts
// ---------------------------------------------------------------
__global__ __launch_bounds__(256) void conv_x(const float* __restrict__ X,
                                              u16* __restrict__ Xb)
{
    size_t i = (size_t)blockIdx.x * 256 + threadIdx.x;
    float4 a = ((const float4*)X)[2*i], b = ((const float4*)X)[2*i + 1];
    u16x8 o;
    o[0]=f2bf(a.x); o[1]=f2bf(a.y); o[2]=f2bf(a.z); o[3]=f2bf(a.w);
    o[4]=f2bf(b.x); o[5]=f2bf(b.y); o[6]=f2bf(b.z); o[7]=f2bf(b.w);
    *(u16x8*)&Xb[8*i] = o;
}

__global__ __launch_bounds__(256) void conv_wt(
    const float* __restrict__ Wq, const float* __restrict__ Wk,
    const float* __restrict__ Wv, const float* __restrict__ Wo,
    u16* __restrict__ Wt)
{
    __shared__ u16 tile[64][65];
    const int t = threadIdx.x;
    const int n0 = blockIdx.x*64, k0 = blockIdx.y*64, mz = blockIdx.z;
    const float* W = mz==0 ? Wq : mz==1 ? Wk : mz==2 ? Wv : Wo;
    u16* Wd = Wt + (size_t)mz * 1024 * 1024;
    #pragma unroll
    for (int p = 0; p < 4; ++p) {
        int r = p*16 + (t>>4), c = (t&15)*4;
        float4 v = *(const float4*)&W[(size_t)(k0+r)*1024 + n0 + c];
        tile[c+0][r]=f2bf(v.x); tile[c+1][r]=f2bf(v.y);
        tile[c+2][r]=f2bf(v.z); tile[c+3][r]=f2bf(v.w);
    }
    __syncthreads();
    #pragma unroll
    for (int p = 0; p < 4; ++p) {
        int nr = p*16 + (t>>4), kc = (t&15)*4;
        u16x4 o = { tile[nr][kc], tile[nr][kc+1], tile[nr][kc+2], tile[nr][kc+3] };
        *(u16x4*)&Wd[(size_t)(n0+nr)*1024 + k0 + kc] = o;
    }
}

__global__ __launch_bounds__(256) void transpose_v(const u16* __restrict__ Vb,
                                                   u16* __restrict__ Vt)
{
    __shared__ u16 tile[64][65];
    const int t = threadIdx.x;
    const int c0 = blockIdx.x*64, r0 = blockIdx.y*64;
    #pragma unroll
    for (int p = 0; p < 4; ++p) {
        int r = p*16 + (t>>4), c = (t&15)*4;
        u16x4 v = *(const u16x4*)&Vb[(size_t)(r0+r)*1024 + c0 + c];
        tile[c+0][r]=v[0]; tile[c+1][r]=v[1]; tile[c+2][r]=v[2]; tile[c+3][r]=v[3];
    }
    __syncthreads();
    #pragma unroll
    for (int p = 0; p < 4; ++p) {
        int cr = p*16 + (t>>4), rc = (t&15)*4;
        u16x4 o = { tile[cr][rc], tile[cr][rc+1], tile[cr][rc+2], tile[cr][rc+3] };
        *(u16x4*)&Vt[(size_t)(c0+cr)*1024 + r0 + rc] = o;
    }
}

// ---------------------------------------------------------------
// C[e][l][h] = dot(edge_feat[e], edge_weight[l][h]) ; row E = 0
// Output bf16 (halves gather bytes; C fits in per-XCD L2).
// ---------------------------------------------------------------
__global__ __launch_bounds__(256) void edge_pre_kernel(
    const float* __restrict__ EF, const float* __restrict__ EW, u16* __restrict__ C)
{
    __shared__ float ews[64][66];
    __shared__ float ef[16][64];
    const int t = threadIdx.x;
    const int e0 = blockIdx.x * 16;
    #pragma unroll
    for (int i = 0; i < 16; ++i) {
        int idx = t + i * 256;
        ews[idx >> 6][idx & 63] = EW[idx];
    }
    #pragma unroll
    for (int i = 0; i < 4; ++i) {
        int idx = t + i * 256;
        int r = idx >> 6, d = idx & 63;
        int e = e0 + r;
        ef[r][d] = (e < E_) ? EF[(size_t)e * 64 + d] : 0.f;
    }
    __syncthreads();
    const int lh = t & 63;
    const int rb = t >> 6;
    #pragma unroll
    for (int j = 0; j < 4; ++j) {
        int r = rb * 4 + j;
        int e = e0 + r;
        if (e > E_) continue;
        float acc = 0.f;
        if (e < E_) {
            #pragma unroll
            for (int d = 0; d < 64; ++d) acc += ef[r][d] * ews[lh][d];
        }
        C[(size_t)e * 64 + lh] = f2bf(acc);
    }
}

// ---------------------------------------------------------------
// GEMM kernels
// ---------------------------------------------------------------
__global__ __launch_bounds__(256) void qkv_gemm(
    const u16* __restrict__ Xb, const u16* __restrict__ Wt,
    const float* __restrict__ bq, const float* __restrict__ bk,
    const float* __restrict__ bv,
    u16* __restrict__ Qb, u16* __restrict__ Kb, u16* __restrict__ Vb)
{
    __shared__ u16 As[64*64], Bs[128*64];
    const int tid = threadIdx.x;
    const int col0 = blockIdx.x * 128, row0 = blockIdx.y * 64;
    f32x4 acc[2][4] = {};
    gemm_bt_core<64,128>(Xb + (size_t)row0*1024, 1024,
                         Wt + (size_t)col0*1024, 1024, 1024, As, Bs, acc, tid);
    const int l = tid & 63, wm = tid>>7, wn = (tid>>6)&1, lr = l&15, lk = l>>4;
    const int sel = col0 >> 10;
    const float* bias = sel==0 ? bq : sel==1 ? bk : bv;
    u16* O = sel==0 ? Qb : sel==1 ? Kb : Vb;
    const int cbase = col0 & 1023;
    #pragma unroll
    for (int j = 0; j < 4; ++j) {
        int cc = cbase + wn*64 + j*16 + lr;
        float bb = bias[cc];
        #pragma unroll
        for (int i = 0; i < 2; ++i) {
            int rg = row0 + wm*32 + i*16 + lk*4;
            #pragma unroll
            for (int r = 0; r < 4; ++r)
                O[(size_t)(rg + r)*1024 + cc] = f2bf(acc[i][j][r] + bb);
        }
    }
}

__global__ __launch_bounds__(256) void qk_gemm(
    const u16* __restrict__ Qb, const u16* __restrict__ Kb, float* __restrict__ S)
{
    __shared__ u16 As[128*64], Bs[128*64];
    const int tid = threadIdx.x;
    const int col0 = blockIdx.x*128, row0 = blockIdx.y*128, h = blockIdx.z;
    f32x4 acc[4][4] = {};
    gemm_bt_core<128,128>(Qb + (size_t)row0*1024 + h*64, 1024,
                          Kb + (size_t)col0*1024 + h*64, 1024, 64, As, Bs, acc, tid);
    const int l = tid & 63, wm = tid>>7, wn = (tid>>6)&1, lr = l&15, lk = l>>4;
    float* So = S + ((size_t)h << 20);
    #pragma unroll
    for (int j = 0; j < 4; ++j) {
        int cg = col0 + wn*64 + j*16 + lr;
        #pragma unroll
        for (int i = 0; i < 4; ++i) {
            int rg = row0 + wm*64 + i*16 + lk*4;
            #pragma unroll
            for (int r = 0; r < 4; ++r)
                So[(size_t)(rg + r)*1024 + cg] = acc[i][j][r] * SCALE;
        }
    }
}

__global__ __launch_bounds__(256) void pv_gemm(
    const u16* __restrict__ P, const u16* __restrict__ Vt, u16* __restrict__ AO)
{
    __shared__ u16 As[64*64], Bs[64*64];
    const int tid = threadIdx.x;
    const int row0 = blockIdx.x * 64, h = blockIdx.y;
    f32x4 acc[2][2] = {};
    gemm_bt_core<64,64>(P + ((size_t)((h<<10) + row0)) * 2048, 2048,
                        Vt + (size_t)h*64*1024, 1024, 1024, As, Bs, acc, tid);
    const int l = tid & 63, wm = tid>>7, wn = (tid>>6)&1, lr = l&15, lk = l>>4;
    #pragma unroll
    for (int j = 0; j < 2; ++j) {
        int col = h*64 + wn*32 + j*16 + lr;
        #pragma unroll
        for (int i = 0; i < 2; ++i) {
            int rg = row0 + wm*32 + i*16 + lk*4;
            #pragma unroll
            for (int r = 0; r < 4; ++r)
                AO[(size_t)(rg + r)*1024 + col] = f2bf(acc[i][j][r]);
        }
    }
}

__global__ __launch_bounds__(256) void out_gemm(
    const u16* __restrict__ AO, const u16* __restrict__ Wot,
    const float* __restrict__ bo, float* __restrict__ out)
{
    __shared__ u16 As[64*64], Bs[64*64];
    const int tid = threadIdx.x;
    const int col0 = blockIdx.x * 64, row0 = blockIdx.y * 64;
    f32x4 acc[2][2] = {};
    gemm_bt_core<64,64>(AO + (size_t)row0*1024, 1024,
                        Wot + (size_t)col0*1024, 1024, 1024, As, Bs, acc, tid);
    const int l = tid & 63, wm = tid>>7, wn = (tid>>6)&1, lr = l&15, lk = l>>4;
    #pragma unroll
    for (int j = 0; j < 2; ++j) {
        int cg = col0 + wn*32 + j*16 + lr;
        float bb = bo[cg];
        #pragma unroll
        for (int i = 0; i < 2; ++i) {
            int rg = row0 + wm*32 + i*16 + lk*4;
            #pragma unroll
            for (int r = 0; r < 4; ++r)
                out[(size_t)(rg + r)*1024 + cg] = acc[i][j][r] + bb;
        }
    }
}

// ---------------------------------------------------------------
// bias (spatial + edge enc) + mask + softmax; S is fp32 [h][n][m].
// R9 semantics exactly; all 16 C-gathers (both head chunks) are
// issued upfront (chunk-2 payload parked in registers across the
// chunk-1 softmax) for 4x the memory-level parallelism.
// bf16 probs packed into the first 1024 u16 of each fp32 row.
// ---------------------------------------------------------------
__global__ __launch_bounds__(512) void bias_softmax8(
    const int* __restrict__ SD, const int* __restrict__ SP,
    const u16* __restrict__ C, const float* __restrict__ STBL,
    float* __restrict__ S)
{
    __shared__ int   sdl[1024];
    __shared__ float stbl[80];
    __shared__ float bias[8][1024];
    const int t = threadIdx.x;
    const int n = blockIdx.x;
    const int w = t >> 6, lane = t & 63;
    #pragma unroll
    for (int k = 0; k < 2; ++k) {
        int m = t + k*512;
        sdl[m] = SD[(size_t)n*1024 + m];
    }
    const int4 v0 = *(const int4*)&SP[((size_t)n*1024 + t)*4];
    const int4 v1 = *(const int4*)&SP[((size_t)n*1024 + t + 512)*4];
    if (t < 80) stbl[t] = STBL[t];

    // S-row prefetch (T14) — in flight together with the gathers below.
    float2 pre0[8], pre1[8];
    {
        const float* sr0 = S + (((size_t)w << 10) + n) * 1024;
        const float* sr1 = S + (((size_t)(w + 8) << 10) + n) * 1024;
        #pragma unroll
        for (int j = 0; j < 8; ++j) pre0[j] = *(const float2*)&sr0[lane*2 + j*128];
        #pragma unroll
        for (int j = 0; j < 8; ++j) pre1[j] = *(const float2*)&sr1[lane*2 + j*128];
    }
    // issue ALL 16 C-gathers now (4 per k per chunk)
    u16x8 g1[2][4], g2[2][4];
    #pragma unroll
    for (int k = 0; k < 2; ++k) {
        int4 e4 = k ? v1 : v0;
        g1[k][0] = *(const u16x8*)&C[(size_t)e4.x*64 +  0];
        g1[k][1] = *(const u16x8*)&C[(size_t)e4.y*64 + 16];
        g1[k][2] = *(const u16x8*)&C[(size_t)e4.z*64 + 32];
        g1[k][3] = *(const u16x8*)&C[(size_t)e4.w*64 + 48];
        g2[k][0] = *(const u16x8*)&C[(size_t)e4.x*64 +  0 + 8];
        g2[k][1] = *(const u16x8*)&C[(size_t)e4.y*64 + 16 + 8];
        g2[k][2] = *(const u16x8*)&C[(size_t)e4.z*64 + 32 + 8];
        g2[k][3] = *(const u16x8*)&C[(size_t)e4.w*64 + 48 + 8];
    }
    __syncthreads();

    // ---- chunk 1 (heads 0..7) ----
    #pragma unroll
    for (int k = 0; k < 2; ++k) {
        int m   = t + k*512;
        int sdv = sdl[m];
        int cl  = sdv > 4 ? 4 : (sdv < 0 ? 0 : sdv);
        float4 b0 = *(const float4*)&stbl[cl*16];
        float4 b1 = *(const float4*)&stbl[cl*16 + 4];
        bias[0][m] = b0.x + bf2f(g1[k][0][0]) + bf2f(g1[k][1][0]) + bf2f(g1[k][2][0]) + bf2f(g1[k][3][0]);
        bias[1][m] = b0.y + bf2f(g1[k][0][1]) + bf2f(g1[k][1][1]) + bf2f(g1[k][2][1]) + bf2f(g1[k][3][1]);
        bias[2][m] = b0.z + bf2f(g1[k][0][2]) + bf2f(g1[k][1][2]) + bf2f(g1[k][2][2]) + bf2f(g1[k][3][2]);
        bias[3][m] = b0.w + bf2f(g1[k][0][3]) + bf2f(g1[k][1][3]) + bf2f(g1[k][2][3]) + bf2f(g1[k][3][3]);
        bias[4][m] = b1.x + bf2f(g1[k][0][4]) + bf2f(g1[k][1][4]) + bf2f(g1[k][2][4]) + bf2f(g1[k][3][4]);
        bias[5][m] = b1.y + bf2f(g1[k][0][5]) + bf2f(g1[k][1][5]) + bf2f(g1[k][2][5]) + bf2f(g1[k][3][5]);
        bias[6][m] = b1.z + bf2f(g1[k][0][6]) + bf2f(g1[k][1][6]) + bf2f(g1[k][2][6]) + bf2f(g1[k][3][6]);
        bias[7][m] = b1.w + bf2f(g1[k][0][7]) + bf2f(g1[k][1][7]) + bf2f(g1[k][2][7]) + bf2f(g1[k][3][7]);
    }
    __syncthreads();
    #pragma unroll
    for (int hc = 0; hc < 16; hc += 8) {
        if (hc) {
            // ---- chunk 2 bias (heads 8..15) from parked registers ----
            __syncthreads();
            #pragma unroll
            for (int k = 0; k < 2; ++k) {
                int m   = t + k*512;
                int sdv = sdl[m];
                int cl  = sdv > 4 ? 4 : (sdv < 0 ? 0 : sdv);
                float4 b0 = *(const float4*)&stbl[cl*16 + 8];
                float4 b1 = *(const float4*)&stbl[cl*16 + 12];
                bias[0][m] = b0.x + bf2f(g2[k][0][0]) + bf2f(g2[k][1][0]) + bf2f(g2[k][2][0]) + bf2f(g2[k][3][0]);
                bias[1][m] = b0.y + bf2f(g2[k][0][1]) + bf2f(g2[k][1][1]) + bf2f(g2[k][2][1]) + bf2f(g2[k][3][1]);
                bias[2][m] = b0.z + bf2f(g2[k][0][2]) + bf2f(g2[k][1][2]) + bf2f(g2[k][2][2]) + bf2f(g2[k][3][2]);
                bias[3][m] = b0.w + bf2f(g2[k][0][3]) + bf2f(g2[k][1][3]) + bf2f(g2[k][2][3]) + bf2f(g2[k][3][3]);
                bias[4][m] = b1.x + bf2f(g2[k][0][4]) + bf2f(g2[k][1][4]) + bf2f(g2[k][2][4]) + bf2f(g2[k][3][4]);
                bias[5][m] = b1.y + bf2f(g2[k][0][5]) + bf2f(g2[k][1][5]) + bf2f(g2[k][2][5]) + bf2f(g2[k][3][5]);
                bias[6][m] = b1.z + bf2f(g2[k][0][6]) + bf2f(g2[k][1][6]) + bf2f(g2[k][2][6]) + bf2f(g2[k][3][6]);
                bias[7][m] = b1.w + bf2f(g2[k][0][7]) + bf2f(g2[k][1][7]) + bf2f(g2[k][2][7]) + bf2f(g2[k][3][7]);
            }
            __syncthreads();
        }
        const int h = hc + w;
        float* srow = S + (((size_t)h << 10) + n) * 1024;
        float v[16];
        float lmax = -INFINITY;
        #pragma unroll
        for (int j = 0; j < 8; ++j) {
            int m = lane*2 + j*128;
            float2 sv = hc ? pre1[j] : pre0[j];
            float2 bb = *(const float2*)&bias[w][m];
            int2 sd2 = *(const int2*)&sdl[m];
            float x0 = (sd2.x <= 0) ? -INFINITY : sv.x + bb.x;
            float x1 = (sd2.y <= 0) ? -INFINITY : sv.y + bb.y;
            v[2*j] = x0; v[2*j+1] = x1;
            lmax = fmaxf(lmax, fmaxf(x0, x1));
        }
        #pragma unroll
        for (int o = 32; o; o >>= 1) lmax = fmaxf(lmax, __shfl_xor(lmax, o));
        float lsum = 0.f;
        #pragma unroll
        for (int j = 0; j < 16; ++j) { v[j] = __expf(v[j] - lmax); lsum += v[j]; }
        #pragma unroll
        for (int o = 32; o; o >>= 1) lsum += __shfl_xor(lsum, o);
        float inv = 1.f / lsum;
        u16* prow = (u16*)srow;
        #pragma unroll
        for (int j = 0; j < 8; ++j) {
            int m = lane*2 + j*128;
            u32 pk = ((u32)f2bf(v[2*j+1] * inv) << 16) | f2bf(v[2*j] * inv);
            *(u32*)&prow[m] = pk;
        }
    }
}

// ---------------------------------------------------------------
extern "C" void kernel_launch(void* const* d_in, const int* in_sizes, int n_in,
                              void* d_out, int out_size, void* d_ws, size_t ws_size,
                              hipStream_t stream)
{
    const float* node_feat = (const float*)d_in[0];
    const float* edge_feat = (const float*)d_in[1];
    const int*   sd        = (const int*)d_in[3];
    const int*   sp        = (const int*)d_in[4];
    const float* Wq = (const float*)d_in[6];
    const float* bq = (const float*)d_in[7];
    const float* Wk = (const float*)d_in[8];
    const float* bk = (const float*)d_in[9];
    const float* Wv = (const float*)d_in[10];
    const float* bv = (const float*)d_in[11];
    const float* Wo = (const float*)d_in[12];
    const float* bo = (const float*)d_in[13];
    const float* spatial = (const float*)d_in[14];
    const float* ew      = (const float*)d_in[15];
    float* out = (float*)d_out;

    char* base = (char*)d_ws;
    u16*   Xb = (u16*)(base);                           // 2MB (later Vt)
    u16*   Qb = (u16*)(base + ((size_t)2 << 20));       // 2MB (later attnout)
    u16*   Kb = (u16*)(base + ((size_t)4 << 20));       // 2MB
    u16*   Vb = (u16*)(base + ((size_t)6 << 20));       // 2MB
    u16*   Wt = (u16*)(base + ((size_t)8 << 20));       // 8MB
    u16*   C  = (u16*)(base + ((size_t)16 << 20));      // 2,097,280 B (bf16)
    float* S  = (float*)(base + ((size_t)19 << 20));    // 64MB fp32
    u16*   Vt = Xb;   // alias: Xb dead after qkv_gemm
    u16*   AO = Qb;   // alias: Qb dead after qk_gemm

    conv_x<<<512, 256, 0, stream>>>(node_feat, Xb);
    conv_wt<<<dim3(16,16,4), 256, 0, stream>>>(Wq, Wk, Wv, Wo, Wt);
    edge_pre_kernel<<<dim3(E_/16 + 1), 256, 0, stream>>>(edge_feat, ew, C);
    qkv_gemm<<<dim3(24,16), 256, 0, stream>>>(Xb, Wt, bq, bk, bv, Qb, Kb, Vb);
    transpose_v<<<dim3(16,16), 256, 0, stream>>>(Vb, Vt);
    qk_gemm<<<dim3(8,8,16), 256, 0, stream>>>(Qb, Kb, S);
    bias_softmax8<<<dim3(1024), 512, 0, stream>>>(sd, sp, C, spatial, S);
    pv_gemm<<<dim3(16,16), 256, 0, stream>>>((const u16*)S, Vt, AO);
    out_gemm<<<dim3(16,16), 256, 0, stream>>>(AO, Wt + (size_t)3*1024*1024, bo, out);
}

// Round 12
// 127.321 us; speedup vs baseline: 1.1592x; 1.0054x over previous
//
#include <hip/hip_runtime.h>
#include <math.h>

#define N_    1024
#define H_    16
#define E_    16384
#define SCALE 0.125f

typedef unsigned short u16;
typedef unsigned int   u32;
typedef short  short8v __attribute__((ext_vector_type(8)));
typedef float  f32x4   __attribute__((ext_vector_type(4)));
typedef u16    u16x4   __attribute__((ext_vector_type(4)));
typedef u16    u16x8   __attribute__((ext_vector_type(8)));

__device__ __forceinline__ u16 f2bf(float f) {
    union { float f; unsigned u; } v; v.f = f;
    unsigned r = v.u + 0x7fffu + ((v.u >> 16) & 1u);
    return (u16)(r >> 16);
}
__device__ __forceinline__ float bf2f(u16 u) {
    union { unsigned u; float f; } v; v.u = (u32)u << 16; return v.f;
}

// ---------------------------------------------------------------
// staging: global(bf16, row-major, ld=ldr) -> LDS tile [rows][64]
// XOR slot swizzle applied on the GLOBAL source (linear LDS dest).
// ---------------------------------------------------------------
template<int U64>
__device__ __forceinline__ void stage_bt(const u16* __restrict__ g, int ldr,
                                         u16* s, int tid)
{
    const int l = tid & 63, w = tid >> 6;
    for (int c = w; c < U64; c += 4) {
        int o16 = (c << 6) + l;
        int row = o16 >> 3;
        int ss  = (o16 & 7) ^ (row & 7);
        const u16* gp = g + (size_t)row * ldr + (ss << 3);
        u16* lp = s + (c << 9);
        __builtin_amdgcn_global_load_lds(
            (const __attribute__((address_space(1))) void*)gp,
            (__attribute__((address_space(3))) void*)lp, 16, 0, 0);
    }
}

__device__ __forceinline__ short8v frag_read(const u16* s, int row, int slot) {
    return *(const short8v*)(s + row * 64 + ((slot ^ (row & 7)) << 3));
}

// ---------------------------------------------------------------
// bf16 GEMM-BT core: block tile MT x NT, 4 waves (2x2), BK=64.
// Per-element accumulation order identical for all MT/NT.
// ---------------------------------------------------------------
template<int MT, int NT>
__device__ __forceinline__ void gemm_bt_core(
    const u16* __restrict__ At, int lda,
    const u16* __restrict__ Bt, int ldb,
    int K, u16* As, u16* Bs, f32x4 (&acc)[MT/32][NT/32], int tid)
{
    const int l  = tid & 63;
    const int wm = tid >> 7, wn = (tid >> 6) & 1;
    const int lr = l & 15,   lk = l >> 4;
    for (int k0 = 0; k0 < K; k0 += 64) {
        if (k0) __syncthreads();
        stage_bt<MT/8>(At + k0, lda, As, tid);
        stage_bt<NT/8>(Bt + k0, ldb, Bs, tid);
        __syncthreads();
        #pragma unroll
        for (int s = 0; s < 2; ++s) {
            short8v af[MT/32], bfv[NT/32];
            #pragma unroll
            for (int i = 0; i < MT/32; ++i)
                af[i] = frag_read(As, wm*(MT/2) + i*16 + lr, s*4 + lk);
            #pragma unroll
            for (int j = 0; j < NT/32; ++j)
                bfv[j] = frag_read(Bs, wn*(NT/2) + j*16 + lr, s*4 + lk);
            #pragma unroll
            for (int i = 0; i < MT/32; ++i)
                #pragma unroll
                for (int j = 0; j < NT/32; ++j)
                    asm("v_mfma_f32_16x16x32_bf16 %0, %1, %2, %0"
                        : "+v"(acc[i][j]) : "v"(af[i]), "v"(bfv[j]));
        }
    }
    __syncthreads();
}

// ---------------------------------------------------------------
// converts
// ---------------------------------------------------------------
__global__ __launch_bounds__(256) void conv_x(const float* __restrict__ X,
                                              u16* __restrict__ Xb)
{
    size_t i = (size_t)blockIdx.x * 256 + threadIdx.x;
    float4 a = ((const float4*)X)[2*i], b = ((const float4*)X)[2*i + 1];
    u16x8 o;
    o[0]=f2bf(a.x); o[1]=f2bf(a.y); o[2]=f2bf(a.z); o[3]=f2bf(a.w);
    o[4]=f2bf(b.x); o[5]=f2bf(b.y); o[6]=f2bf(b.z); o[7]=f2bf(b.w);
    *(u16x8*)&Xb[8*i] = o;
}

__global__ __launch_bounds__(256) void conv_wt(
    const float* __restrict__ Wq, const float* __restrict__ Wk,
    const float* __restrict__ Wv, const float* __restrict__ Wo,
    u16* __restrict__ Wt)
{
    __shared__ u16 tile[64][65];
    const int t = threadIdx.x;
    const int n0 = blockIdx.x*64, k0 = blockIdx.y*64, mz = blockIdx.z;
    const float* W = mz==0 ? Wq : mz==1 ? Wk : mz==2 ? Wv : Wo;
    u16* Wd = Wt + (size_t)mz * 1024 * 1024;
    #pragma unroll
    for (int p = 0; p < 4; ++p) {
        int r = p*16 + (t>>4), c = (t&15)*4;
        float4 v = *(const float4*)&W[(size_t)(k0+r)*1024 + n0 + c];
        tile[c+0][r]=f2bf(v.x); tile[c+1][r]=f2bf(v.y);
        tile[c+2][r]=f2bf(v.z); tile[c+3][r]=f2bf(v.w);
    }
    __syncthreads();
    #pragma unroll
    for (int p = 0; p < 4; ++p) {
        int nr = p*16 + (t>>4), kc = (t&15)*4;
        u16x4 o = { tile[nr][kc], tile[nr][kc+1], tile[nr][kc+2], tile[nr][kc+3] };
        *(u16x4*)&Wd[(size_t)(n0+nr)*1024 + k0 + kc] = o;
    }
}

__global__ __launch_bounds__(256) void transpose_v(const u16* __restrict__ Vb,
                                                   u16* __restrict__ Vt)
{
    __shared__ u16 tile[64][65];
    const int t = threadIdx.x;
    const int c0 = blockIdx.x*64, r0 = blockIdx.y*64;
    #pragma unroll
    for (int p = 0; p < 4; ++p) {
        int r = p*16 + (t>>4), c = (t&15)*4;
        u16x4 v = *(const u16x4*)&Vb[(size_t)(r0+r)*1024 + c0 + c];
        tile[c+0][r]=v[0]; tile[c+1][r]=v[1]; tile[c+2][r]=v[2]; tile[c+3][r]=v[3];
    }
    __syncthreads();
    #pragma unroll
    for (int p = 0; p < 4; ++p) {
        int cr = p*16 + (t>>4), rc = (t&15)*4;
        u16x4 o = { tile[cr][rc], tile[cr][rc+1], tile[cr][rc+2], tile[cr][rc+3] };
        *(u16x4*)&Vt[(size_t)(c0+cr)*1024 + r0 + rc] = o;
    }
}

// ---------------------------------------------------------------
// C[e][l][h] = dot(edge_feat[e], edge_weight[l][h]) ; row E = 0
// Output bf16 (halves gather bytes; C fits in per-XCD L2).
// ---------------------------------------------------------------
__global__ __launch_bounds__(256) void edge_pre_kernel(
    const float* __restrict__ EF, const float* __restrict__ EW, u16* __restrict__ C)
{
    __shared__ float ews[64][66];
    __shared__ float ef[16][64];
    const int t = threadIdx.x;
    const int e0 = blockIdx.x * 16;
    #pragma unroll
    for (int i = 0; i < 16; ++i) {
        int idx = t + i * 256;
        ews[idx >> 6][idx & 63] = EW[idx];
    }
    #pragma unroll
    for (int i = 0; i < 4; ++i) {
        int idx = t + i * 256;
        int r = idx >> 6, d = idx & 63;
        int e = e0 + r;
        ef[r][d] = (e < E_) ? EF[(size_t)e * 64 + d] : 0.f;
    }
    __syncthreads();
    const int lh = t & 63;
    const int rb = t >> 6;
    #pragma unroll
    for (int j = 0; j < 4; ++j) {
        int r = rb * 4 + j;
        int e = e0 + r;
        if (e > E_) continue;
        float acc = 0.f;
        if (e < E_) {
            #pragma unroll
            for (int d = 0; d < 64; ++d) acc += ef[r][d] * ews[lh][d];
        }
        C[(size_t)e * 64 + lh] = f2bf(acc);
    }
}

// ---------------------------------------------------------------
// GEMM kernels
// ---------------------------------------------------------------
__global__ __launch_bounds__(256) void qkv_gemm(
    const u16* __restrict__ Xb, const u16* __restrict__ Wt,
    const float* __restrict__ bq, const float* __restrict__ bk,
    const float* __restrict__ bv,
    u16* __restrict__ Qb, u16* __restrict__ Kb, u16* __restrict__ Vb)
{
    __shared__ u16 As[64*64], Bs[128*64];
    const int tid = threadIdx.x;
    const int col0 = blockIdx.x * 128, row0 = blockIdx.y * 64;
    f32x4 acc[2][4] = {};
    gemm_bt_core<64,128>(Xb + (size_t)row0*1024, 1024,
                         Wt + (size_t)col0*1024, 1024, 1024, As, Bs, acc, tid);
    const int l = tid & 63, wm = tid>>7, wn = (tid>>6)&1, lr = l&15, lk = l>>4;
    const int sel = col0 >> 10;
    const float* bias = sel==0 ? bq : sel==1 ? bk : bv;
    u16* O = sel==0 ? Qb : sel==1 ? Kb : Vb;
    const int cbase = col0 & 1023;
    #pragma unroll
    for (int j = 0; j < 4; ++j) {
        int cc = cbase + wn*64 + j*16 + lr;
        float bb = bias[cc];
        #pragma unroll
        for (int i = 0; i < 2; ++i) {
            int rg = row0 + wm*32 + i*16 + lk*4;
            #pragma unroll
            for (int r = 0; r < 4; ++r)
                O[(size_t)(rg + r)*1024 + cc] = f2bf(acc[i][j][r] + bb);
        }
    }
}

__global__ __launch_bounds__(256) void qk_gemm(
    const u16* __restrict__ Qb, const u16* __restrict__ Kb, float* __restrict__ S)
{
    __shared__ u16 As[128*64], Bs[128*64];
    const int tid = threadIdx.x;
    const int col0 = blockIdx.x*128, row0 = blockIdx.y*128, h = blockIdx.z;
    f32x4 acc[4][4] = {};
    gemm_bt_core<128,128>(Qb + (size_t)row0*1024 + h*64, 1024,
                          Kb + (size_t)col0*1024 + h*64, 1024, 64, As, Bs, acc, tid);
    const int l = tid & 63, wm = tid>>7, wn = (tid>>6)&1, lr = l&15, lk = l>>4;
    float* So = S + ((size_t)h << 20);
    #pragma unroll
    for (int j = 0; j < 4; ++j) {
        int cg = col0 + wn*64 + j*16 + lr;
        #pragma unroll
        for (int i = 0; i < 4; ++i) {
            int rg = row0 + wm*64 + i*16 + lk*4;
            #pragma unroll
            for (int r = 0; r < 4; ++r)
                So[(size_t)(rg + r)*1024 + cg] = acc[i][j][r] * SCALE;
        }
    }
}

__global__ __launch_bounds__(256) void pv_gemm(
    const u16* __restrict__ P, const u16* __restrict__ Vt, u16* __restrict__ AO)
{
    __shared__ u16 As[64*64], Bs[64*64];
    const int tid = threadIdx.x;
    const int row0 = blockIdx.x * 64, h = blockIdx.y;
    f32x4 acc[2][2] = {};
    gemm_bt_core<64,64>(P + ((size_t)((h<<10) + row0)) * 2048, 2048,
                        Vt + (size_t)h*64*1024, 1024, 1024, As, Bs, acc, tid);
    const int l = tid & 63, wm = tid>>7, wn = (tid>>6)&1, lr = l&15, lk = l>>4;
    #pragma unroll
    for (int j = 0; j < 2; ++j) {
        int col = h*64 + wn*32 + j*16 + lr;
        #pragma unroll
        for (int i = 0; i < 2; ++i) {
            int rg = row0 + wm*32 + i*16 + lk*4;
            #pragma unroll
            for (int r = 0; r < 4; ++r)
                AO[(size_t)(rg + r)*1024 + col] = f2bf(acc[i][j][r]);
        }
    }
}

__global__ __launch_bounds__(256) void out_gemm(
    const u16* __restrict__ AO, const u16* __restrict__ Wot,
    const float* __restrict__ bo, float* __restrict__ out)
{
    __shared__ u16 As[64*64], Bs[64*64];
    const int tid = threadIdx.x;
    const int col0 = blockIdx.x * 64, row0 = blockIdx.y * 64;
    f32x4 acc[2][2] = {};
    gemm_bt_core<64,64>(AO + (size_t)row0*1024, 1024,
                        Wot + (size_t)col0*1024, 1024, 1024, As, Bs, acc, tid);
    const int l = tid & 63, wm = tid>>7, wn = (tid>>6)&1, lr = l&15, lk = l>>4;
    #pragma unroll
    for (int j = 0; j < 2; ++j) {
        int cg = col0 + wn*32 + j*16 + lr;
        float bb = bo[cg];
        #pragma unroll
        for (int i = 0; i < 2; ++i) {
            int rg = row0 + wm*32 + i*16 + lk*4;
            #pragma unroll
            for (int r = 0; r < 4; ++r)
                out[(size_t)(rg + r)*1024 + cg] = acc[i][j][r] + bb;
        }
    }
}

// ---------------------------------------------------------------
// bias (spatial + edge enc) + mask + softmax; S is fp32 [h][n][m].
// R10 structure exactly (proven stable through full validation):
// one block per n, both head chunks in-block, all 16 C-gathers
// issued upfront, chunk-2 payload parked in registers.
// bf16 probs packed into the first 1024 u16 of each fp32 row.
// ---------------------------------------------------------------
__global__ __launch_bounds__(512) void bias_softmax8(
    const int* __restrict__ SD, const int* __restrict__ SP,
    const u16* __restrict__ C, const float* __restrict__ STBL,
    float* __restrict__ S)
{
    __shared__ int   sdl[1024];
    __shared__ float stbl[80];
    __shared__ float bias[8][1024];
    const int t = threadIdx.x;
    const int n = blockIdx.x;
    const int w = t >> 6, lane = t & 63;
    #pragma unroll
    for (int k = 0; k < 2; ++k) {
        int m = t + k*512;
        sdl[m] = SD[(size_t)n*1024 + m];
    }
    const int4 v0 = *(const int4*)&SP[((size_t)n*1024 + t)*4];
    const int4 v1 = *(const int4*)&SP[((size_t)n*1024 + t + 512)*4];
    if (t < 80) stbl[t] = STBL[t];

    // S-row prefetch (T14) — in flight together with the gathers below.
    float2 pre0[8], pre1[8];
    {
        const float* sr0 = S + (((size_t)w << 10) + n) * 1024;
        const float* sr1 = S + (((size_t)(w + 8) << 10) + n) * 1024;
        #pragma unroll
        for (int j = 0; j < 8; ++j) pre0[j] = *(const float2*)&sr0[lane*2 + j*128];
        #pragma unroll
        for (int j = 0; j < 8; ++j) pre1[j] = *(const float2*)&sr1[lane*2 + j*128];
    }
    // issue ALL 16 C-gathers now (4 per k per chunk)
    u16x8 g1[2][4], g2[2][4];
    #pragma unroll
    for (int k = 0; k < 2; ++k) {
        int4 e4 = k ? v1 : v0;
        g1[k][0] = *(const u16x8*)&C[(size_t)e4.x*64 +  0];
        g1[k][1] = *(const u16x8*)&C[(size_t)e4.y*64 + 16];
        g1[k][2] = *(const u16x8*)&C[(size_t)e4.z*64 + 32];
        g1[k][3] = *(const u16x8*)&C[(size_t)e4.w*64 + 48];
        g2[k][0] = *(const u16x8*)&C[(size_t)e4.x*64 +  0 + 8];
        g2[k][1] = *(const u16x8*)&C[(size_t)e4.y*64 + 16 + 8];
        g2[k][2] = *(const u16x8*)&C[(size_t)e4.z*64 + 32 + 8];
        g2[k][3] = *(const u16x8*)&C[(size_t)e4.w*64 + 48 + 8];
    }
    __syncthreads();

    // ---- chunk 1 (heads 0..7) ----
    #pragma unroll
    for (int k = 0; k < 2; ++k) {
        int m   = t + k*512;
        int sdv = sdl[m];
        int cl  = sdv > 4 ? 4 : (sdv < 0 ? 0 : sdv);
        float4 b0 = *(const float4*)&stbl[cl*16];
        float4 b1 = *(const float4*)&stbl[cl*16 + 4];
        bias[0][m] = b0.x + bf2f(g1[k][0][0]) + bf2f(g1[k][1][0]) + bf2f(g1[k][2][0]) + bf2f(g1[k][3][0]);
        bias[1][m] = b0.y + bf2f(g1[k][0][1]) + bf2f(g1[k][1][1]) + bf2f(g1[k][2][1]) + bf2f(g1[k][3][1]);
        bias[2][m] = b0.z + bf2f(g1[k][0][2]) + bf2f(g1[k][1][2]) + bf2f(g1[k][2][2]) + bf2f(g1[k][3][2]);
        bias[3][m] = b0.w + bf2f(g1[k][0][3]) + bf2f(g1[k][1][3]) + bf2f(g1[k][2][3]) + bf2f(g1[k][3][3]);
        bias[4][m] = b1.x + bf2f(g1[k][0][4]) + bf2f(g1[k][1][4]) + bf2f(g1[k][2][4]) + bf2f(g1[k][3][4]);
        bias[5][m] = b1.y + bf2f(g1[k][0][5]) + bf2f(g1[k][1][5]) + bf2f(g1[k][2][5]) + bf2f(g1[k][3][5]);
        bias[6][m] = b1.z + bf2f(g1[k][0][6]) + bf2f(g1[k][1][6]) + bf2f(g1[k][2][6]) + bf2f(g1[k][3][6]);
        bias[7][m] = b1.w + bf2f(g1[k][0][7]) + bf2f(g1[k][1][7]) + bf2f(g1[k][2][7]) + bf2f(g1[k][3][7]);
    }
    __syncthreads();
    #pragma unroll
    for (int hc = 0; hc < 16; hc += 8) {
        if (hc) {
            // ---- chunk 2 bias (heads 8..15) from parked registers ----
            __syncthreads();
            #pragma unroll
            for (int k = 0; k < 2; ++k) {
                int m   = t + k*512;
                int sdv = sdl[m];
                int cl  = sdv > 4 ? 4 : (sdv < 0 ? 0 : sdv);
                float4 b0 = *(const float4*)&stbl[cl*16 + 8];
                float4 b1 = *(const float4*)&stbl[cl*16 + 12];
                bias[0][m] = b0.x + bf2f(g2[k][0][0]) + bf2f(g2[k][1][0]) + bf2f(g2[k][2][0]) + bf2f(g2[k][3][0]);
                bias[1][m] = b0.y + bf2f(g2[k][0][1]) + bf2f(g2[k][1][1]) + bf2f(g2[k][2][1]) + bf2f(g2[k][3][1]);
                bias[2][m] = b0.z + bf2f(g2[k][0][2]) + bf2f(g2[k][1][2]) + bf2f(g2[k][2][2]) + bf2f(g2[k][3][2]);
                bias[3][m] = b0.w + bf2f(g2[k][0][3]) + bf2f(g2[k][1][3]) + bf2f(g2[k][2][3]) + bf2f(g2[k][3][3]);
                bias[4][m] = b1.x + bf2f(g2[k][0][4]) + bf2f(g2[k][1][4]) + bf2f(g2[k][2][4]) + bf2f(g2[k][3][4]);
                bias[5][m] = b1.y + bf2f(g2[k][0][5]) + bf2f(g2[k][1][5]) + bf2f(g2[k][2][5]) + bf2f(g2[k][3][5]);
                bias[6][m] = b1.z + bf2f(g2[k][0][6]) + bf2f(g2[k][1][6]) + bf2f(g2[k][2][6]) + bf2f(g2[k][3][6]);
                bias[7][m] = b1.w + bf2f(g2[k][0][7]) + bf2f(g2[k][1][7]) + bf2f(g2[k][2][7]) + bf2f(g2[k][3][7]);
            }
            __syncthreads();
        }
        const int h = hc + w;
        float* srow = S + (((size_t)h << 10) + n) * 1024;
        float v[16];
        float lmax = -INFINITY;
        #pragma unroll
        for (int j = 0; j < 8; ++j) {
            int m = lane*2 + j*128;
            float2 sv = hc ? pre1[j] : pre0[j];
            float2 bb = *(const float2*)&bias[w][m];
            int2 sd2 = *(const int2*)&sdl[m];
            float x0 = (sd2.x <= 0) ? -INFINITY : sv.x + bb.x;
            float x1 = (sd2.y <= 0) ? -INFINITY : sv.y + bb.y;
            v[2*j] = x0; v[2*j+1] = x1;
            lmax = fmaxf(lmax, fmaxf(x0, x1));
        }
        #pragma unroll
        for (int o = 32; o; o >>= 1) lmax = fmaxf(lmax, __shfl_xor(lmax, o));
        float lsum = 0.f;
        #pragma unroll
        for (int j = 0; j < 16; ++j) { v[j] = __expf(v[j] - lmax); lsum += v[j]; }
        #pragma unroll
        for (int o = 32; o; o >>= 1) lsum += __shfl_xor(lsum, o);
        float inv = 1.f / lsum;
        u16* prow = (u16*)srow;
        #pragma unroll
        for (int j = 0; j < 8; ++j) {
            int m = lane*2 + j*128;
            u32 pk = ((u32)f2bf(v[2*j+1] * inv) << 16) | f2bf(v[2*j] * inv);
            *(u32*)&prow[m] = pk;
        }
    }
}

// ---------------------------------------------------------------
extern "C" void kernel_launch(void* const* d_in, const int* in_sizes, int n_in,
                              void* d_out, int out_size, void* d_ws, size_t ws_size,
                              hipStream_t stream)
{
    const float* node_feat = (const float*)d_in[0];
    const float* edge_feat = (const float*)d_in[1];
    const int*   sd        = (const int*)d_in[3];
    const int*   sp        = (const int*)d_in[4];
    const float* Wq = (const float*)d_in[6];
    const float* bq = (const float*)d_in[7];
    const float* Wk = (const float*)d_in[8];
    const float* bk = (const float*)d_in[9];
    const float* Wv = (const float*)d_in[10];
    const float* bv = (const float*)d_in[11];
    const float* Wo = (const float*)d_in[12];
    const float* bo = (const float*)d_in[13];
    const float* spatial = (const float*)d_in[14];
    const float* ew      = (const float*)d_in[15];
    float* out = (float*)d_out;

    char* base = (char*)d_ws;
    u16*   Xb = (u16*)(base);                           // 2MB (later Vt)
    u16*   Qb = (u16*)(base + ((size_t)2 << 20));       // 2MB (later attnout)
    u16*   Kb = (u16*)(base + ((size_t)4 << 20));       // 2MB
    u16*   Vb = (u16*)(base + ((size_t)6 << 20));       // 2MB
    u16*   Wt = (u16*)(base + ((size_t)8 << 20));       // 8MB
    u16*   C  = (u16*)(base + ((size_t)16 << 20));      // 2,097,280 B (bf16)
    float* S  = (float*)(base + ((size_t)19 << 20));    // 64MB fp32
    u16*   Vt = Xb;   // alias: Xb dead after qkv_gemm
    u16*   AO = Qb;   // alias: Qb dead after qk_gemm

    conv_x<<<512, 256, 0, stream>>>(node_feat, Xb);
    conv_wt<<<dim3(16,16,4), 256, 0, stream>>>(Wq, Wk, Wv, Wo, Wt);
    edge_pre_kernel<<<dim3(E_/16 + 1), 256, 0, stream>>>(edge_feat, ew, C);
    qkv_gemm<<<dim3(24,16), 256, 0, stream>>>(Xb, Wt, bq, bk, bv, Qb, Kb, Vb);
    transpose_v<<<dim3(16,16), 256, 0, stream>>>(Vb, Vt);
    qk_gemm<<<dim3(8,8,16), 256, 0, stream>>>(Qb, Kb, S);
    bias_softmax8<<<dim3(1024), 512, 0, stream>>>(sd, sp, C, spatial, S);
    pv_gemm<<<dim3(16,16), 256, 0, stream>>>((const u16*)S, Vt, AO);
    out_gemm<<<dim3(16,16), 256, 0, stream>>>(AO, Wt + (size_t)3*1024*1024, bo, out);
}

// Round 13
// 120.209 us; speedup vs baseline: 1.2278x; 1.0592x over previous
//
#include <hip/hip_runtime.h>
#include <math.h>

#define N_    1024
#define H_    16
#define E_    16384
#define SCALE 0.125f

typedef unsigned short u16;
typedef unsigned int   u32;
typedef short  short8v __attribute__((ext_vector_type(8)));
typedef float  f32x4   __attribute__((ext_vector_type(4)));
typedef u16    u16x4   __attribute__((ext_vector_type(4)));
typedef u16    u16x8   __attribute__((ext_vector_type(8)));

__device__ __forceinline__ u16 f2bf(float f) {
    union { float f; unsigned u; } v; v.f = f;
    unsigned r = v.u + 0x7fffu + ((v.u >> 16) & 1u);
    return (u16)(r >> 16);
}
__device__ __forceinline__ float bf2f(u16 u) {
    union { unsigned u; float f; } v; v.u = (u32)u << 16; return v.f;
}
__device__ __forceinline__ u16 f2h(float f) {
    union { _Float16 h; u16 u; } v; v.h = (_Float16)f; return v.u;
}
__device__ __forceinline__ float h2f(u16 u) {
    union { _Float16 h; u16 u; } v; v.u = u; return (float)v.h;
}

// ---------------------------------------------------------------
// staging: global(bf16, row-major, ld=ldr) -> LDS tile [rows][64]
// XOR slot swizzle applied on the GLOBAL source (linear LDS dest).
// ---------------------------------------------------------------
template<int U64>
__device__ __forceinline__ void stage_bt(const u16* __restrict__ g, int ldr,
                                         u16* s, int tid)
{
    const int l = tid & 63, w = tid >> 6;
    for (int c = w; c < U64; c += 4) {
        int o16 = (c << 6) + l;
        int row = o16 >> 3;
        int ss  = (o16 & 7) ^ (row & 7);
        const u16* gp = g + (size_t)row * ldr + (ss << 3);
        u16* lp = s + (c << 9);
        __builtin_amdgcn_global_load_lds(
            (const __attribute__((address_space(1))) void*)gp,
            (__attribute__((address_space(3))) void*)lp, 16, 0, 0);
    }
}

__device__ __forceinline__ short8v frag_read(const u16* s, int row, int slot) {
    return *(const short8v*)(s + row * 64 + ((slot ^ (row & 7)) << 3));
}

// ---------------------------------------------------------------
// bf16 GEMM-BT core: block tile MT x NT, 4 waves (2x2), BK=64.
// Per-element accumulation order identical for all MT/NT.
// ---------------------------------------------------------------
template<int MT, int NT>
__device__ __forceinline__ void gemm_bt_core(
    const u16* __restrict__ At, int lda,
    const u16* __restrict__ Bt, int ldb,
    int K, u16* As, u16* Bs, f32x4 (&acc)[MT/32][NT/32], int tid)
{
    const int l  = tid & 63;
    const int wm = tid >> 7, wn = (tid >> 6) & 1;
    const int lr = l & 15,   lk = l >> 4;
    for (int k0 = 0; k0 < K; k0 += 64) {
        if (k0) __syncthreads();
        stage_bt<MT/8>(At + k0, lda, As, tid);
        stage_bt<NT/8>(Bt + k0, ldb, Bs, tid);
        __syncthreads();
        #pragma unroll
        for (int s = 0; s < 2; ++s) {
            short8v af[MT/32], bfv[NT/32];
            #pragma unroll
            for (int i = 0; i < MT/32; ++i)
                af[i] = frag_read(As, wm*(MT/2) + i*16 + lr, s*4 + lk);
            #pragma unroll
            for (int j = 0; j < NT/32; ++j)
                bfv[j] = frag_read(Bs, wn*(NT/2) + j*16 + lr, s*4 + lk);
            #pragma unroll
            for (int i = 0; i < MT/32; ++i)
                #pragma unroll
                for (int j = 0; j < NT/32; ++j)
                    asm("v_mfma_f32_16x16x32_bf16 %0, %1, %2, %0"
                        : "+v"(acc[i][j]) : "v"(af[i]), "v"(bfv[j]));
        }
    }
    __syncthreads();
}

// ---------------------------------------------------------------
// converts
// ---------------------------------------------------------------
__global__ __launch_bounds__(256) void conv_x(const float* __restrict__ X,
                                              u16* __restrict__ Xb)
{
    size_t i = (size_t)blockIdx.x * 256 + threadIdx.x;
    float4 a = ((const float4*)X)[2*i], b = ((const float4*)X)[2*i + 1];
    u16x8 o;
    o[0]=f2bf(a.x); o[1]=f2bf(a.y); o[2]=f2bf(a.z); o[3]=f2bf(a.w);
    o[4]=f2bf(b.x); o[5]=f2bf(b.y); o[6]=f2bf(b.z); o[7]=f2bf(b.w);
    *(u16x8*)&Xb[8*i] = o;
}

__global__ __launch_bounds__(256) void conv_wt(
    const float* __restrict__ Wq, const float* __restrict__ Wk,
    const float* __restrict__ Wv, const float* __restrict__ Wo,
    u16* __restrict__ Wt)
{
    __shared__ u16 tile[64][65];
    const int t = threadIdx.x;
    const int n0 = blockIdx.x*64, k0 = blockIdx.y*64, mz = blockIdx.z;
    const float* W = mz==0 ? Wq : mz==1 ? Wk : mz==2 ? Wv : Wo;
    u16* Wd = Wt + (size_t)mz * 1024 * 1024;
    #pragma unroll
    for (int p = 0; p < 4; ++p) {
        int r = p*16 + (t>>4), c = (t&15)*4;
        float4 v = *(const float4*)&W[(size_t)(k0+r)*1024 + n0 + c];
        tile[c+0][r]=f2bf(v.x); tile[c+1][r]=f2bf(v.y);
        tile[c+2][r]=f2bf(v.z); tile[c+3][r]=f2bf(v.w);
    }
    __syncthreads();
    #pragma unroll
    for (int p = 0; p < 4; ++p) {
        int nr = p*16 + (t>>4), kc = (t&15)*4;
        u16x4 o = { tile[nr][kc], tile[nr][kc+1], tile[nr][kc+2], tile[nr][kc+3] };
        *(u16x4*)&Wd[(size_t)(n0+nr)*1024 + k0 + kc] = o;
    }
}

__global__ __launch_bounds__(256) void transpose_v(const u16* __restrict__ Vb,
                                                   u16* __restrict__ Vt)
{
    __shared__ u16 tile[64][65];
    const int t = threadIdx.x;
    const int c0 = blockIdx.x*64, r0 = blockIdx.y*64;
    #pragma unroll
    for (int p = 0; p < 4; ++p) {
        int r = p*16 + (t>>4), c = (t&15)*4;
        u16x4 v = *(const u16x4*)&Vb[(size_t)(r0+r)*1024 + c0 + c];
        tile[c+0][r]=v[0]; tile[c+1][r]=v[1]; tile[c+2][r]=v[2]; tile[c+3][r]=v[3];
    }
    __syncthreads();
    #pragma unroll
    for (int p = 0; p < 4; ++p) {
        int cr = p*16 + (t>>4), rc = (t&15)*4;
        u16x4 o = { tile[cr][rc], tile[cr][rc+1], tile[cr][rc+2], tile[cr][rc+3] };
        *(u16x4*)&Vt[(size_t)(c0+cr)*1024 + r0 + rc] = o;
    }
}

// ---------------------------------------------------------------
// C[e][l][h] = dot(edge_feat[e], edge_weight[l][h]) ; row E = 0
// Output bf16 (halves gather bytes; C fits in per-XCD L2).
// ---------------------------------------------------------------
__global__ __launch_bounds__(256) void edge_pre_kernel(
    const float* __restrict__ EF, const float* __restrict__ EW, u16* __restrict__ C)
{
    __shared__ float ews[64][66];
    __shared__ float ef[16][64];
    const int t = threadIdx.x;
    const int e0 = blockIdx.x * 16;
    #pragma unroll
    for (int i = 0; i < 16; ++i) {
        int idx = t + i * 256;
        ews[idx >> 6][idx & 63] = EW[idx];
    }
    #pragma unroll
    for (int i = 0; i < 4; ++i) {
        int idx = t + i * 256;
        int r = idx >> 6, d = idx & 63;
        int e = e0 + r;
        ef[r][d] = (e < E_) ? EF[(size_t)e * 64 + d] : 0.f;
    }
    __syncthreads();
    const int lh = t & 63;
    const int rb = t >> 6;
    #pragma unroll
    for (int j = 0; j < 4; ++j) {
        int r = rb * 4 + j;
        int e = e0 + r;
        if (e > E_) continue;
        float acc = 0.f;
        if (e < E_) {
            #pragma unroll
            for (int d = 0; d < 64; ++d) acc += ef[r][d] * ews[lh][d];
        }
        C[(size_t)e * 64 + lh] = f2bf(acc);
    }
}

// ---------------------------------------------------------------
// GEMM kernels
// ---------------------------------------------------------------
__global__ __launch_bounds__(256) void qkv_gemm(
    const u16* __restrict__ Xb, const u16* __restrict__ Wt,
    const float* __restrict__ bq, const float* __restrict__ bk,
    const float* __restrict__ bv,
    u16* __restrict__ Qb, u16* __restrict__ Kb, u16* __restrict__ Vb)
{
    __shared__ u16 As[64*64], Bs[128*64];
    const int tid = threadIdx.x;
    const int col0 = blockIdx.x * 128, row0 = blockIdx.y * 64;
    f32x4 acc[2][4] = {};
    gemm_bt_core<64,128>(Xb + (size_t)row0*1024, 1024,
                         Wt + (size_t)col0*1024, 1024, 1024, As, Bs, acc, tid);
    const int l = tid & 63, wm = tid>>7, wn = (tid>>6)&1, lr = l&15, lk = l>>4;
    const int sel = col0 >> 10;
    const float* bias = sel==0 ? bq : sel==1 ? bk : bv;
    u16* O = sel==0 ? Qb : sel==1 ? Kb : Vb;
    const int cbase = col0 & 1023;
    #pragma unroll
    for (int j = 0; j < 4; ++j) {
        int cc = cbase + wn*64 + j*16 + lr;
        float bb = bias[cc];
        #pragma unroll
        for (int i = 0; i < 2; ++i) {
            int rg = row0 + wm*32 + i*16 + lk*4;
            #pragma unroll
            for (int r = 0; r < 4; ++r)
                O[(size_t)(rg + r)*1024 + cc] = f2bf(acc[i][j][r] + bb);
        }
    }
}

// S is fp16 [h][n][m] now (halves the write + softmax read traffic)
__global__ __launch_bounds__(256) void qk_gemm(
    const u16* __restrict__ Qb, const u16* __restrict__ Kb, u16* __restrict__ S)
{
    __shared__ u16 As[128*64], Bs[128*64];
    const int tid = threadIdx.x;
    const int col0 = blockIdx.x*128, row0 = blockIdx.y*128, h = blockIdx.z;
    f32x4 acc[4][4] = {};
    gemm_bt_core<128,128>(Qb + (size_t)row0*1024 + h*64, 1024,
                          Kb + (size_t)col0*1024 + h*64, 1024, 64, As, Bs, acc, tid);
    const int l = tid & 63, wm = tid>>7, wn = (tid>>6)&1, lr = l&15, lk = l>>4;
    u16* So = S + ((size_t)h << 20);
    #pragma unroll
    for (int j = 0; j < 4; ++j) {
        int cg = col0 + wn*64 + j*16 + lr;
        #pragma unroll
        for (int i = 0; i < 4; ++i) {
            int rg = row0 + wm*64 + i*16 + lk*4;
            #pragma unroll
            for (int r = 0; r < 4; ++r)
                So[(size_t)(rg + r)*1024 + cg] = f2h(acc[i][j][r] * SCALE);
        }
    }
}

__global__ __launch_bounds__(256) void pv_gemm(
    const u16* __restrict__ P, const u16* __restrict__ Vt, u16* __restrict__ AO)
{
    __shared__ u16 As[64*64], Bs[64*64];
    const int tid = threadIdx.x;
    const int row0 = blockIdx.x * 64, h = blockIdx.y;
    f32x4 acc[2][2] = {};
    gemm_bt_core<64,64>(P + ((size_t)((h<<10) + row0)) * 1024, 1024,
                        Vt + (size_t)h*64*1024, 1024, 1024, As, Bs, acc, tid);
    const int l = tid & 63, wm = tid>>7, wn = (tid>>6)&1, lr = l&15, lk = l>>4;
    #pragma unroll
    for (int j = 0; j < 2; ++j) {
        int col = h*64 + wn*32 + j*16 + lr;
        #pragma unroll
        for (int i = 0; i < 2; ++i) {
            int rg = row0 + wm*32 + i*16 + lk*4;
            #pragma unroll
            for (int r = 0; r < 4; ++r)
                AO[(size_t)(rg + r)*1024 + col] = f2bf(acc[i][j][r]);
        }
    }
}

__global__ __launch_bounds__(256) void out_gemm(
    const u16* __restrict__ AO, const u16* __restrict__ Wot,
    const float* __restrict__ bo, float* __restrict__ out)
{
    __shared__ u16 As[64*64], Bs[64*64];
    const int tid = threadIdx.x;
    const int col0 = blockIdx.x * 64, row0 = blockIdx.y * 64;
    f32x4 acc[2][2] = {};
    gemm_bt_core<64,64>(AO + (size_t)row0*1024, 1024,
                        Wot + (size_t)col0*1024, 1024, 1024, As, Bs, acc, tid);
    const int l = tid & 63, wm = tid>>7, wn = (tid>>6)&1, lr = l&15, lk = l>>4;
    #pragma unroll
    for (int j = 0; j < 2; ++j) {
        int cg = col0 + wn*32 + j*16 + lr;
        float bb = bo[cg];
        #pragma unroll
        for (int i = 0; i < 2; ++i) {
            int rg = row0 + wm*32 + i*16 + lk*4;
            #pragma unroll
            for (int r = 0; r < 4; ++r)
                out[(size_t)(rg + r)*1024 + cg] = acc[i][j][r] + bb;
        }
    }
}

// ---------------------------------------------------------------
// bias (spatial + edge enc) + mask + softmax; S is fp16 [h][n][m].
// R10/R12 structure exactly (proven stable); fp16 row reads, bf16
// probs overwrite the same u16 slots in place (row stride 1024).
// ---------------------------------------------------------------
__global__ __launch_bounds__(512) void bias_softmax8(
    const int* __restrict__ SD, const int* __restrict__ SP,
    const u16* __restrict__ C, const float* __restrict__ STBL,
    u16* __restrict__ S)
{
    __shared__ int   sdl[1024];
    __shared__ float stbl[80];
    __shared__ float bias[8][1024];
    const int t = threadIdx.x;
    const int n = blockIdx.x;
    const int w = t >> 6, lane = t & 63;
    #pragma unroll
    for (int k = 0; k < 2; ++k) {
        int m = t + k*512;
        sdl[m] = SD[(size_t)n*1024 + m];
    }
    const int4 v0 = *(const int4*)&SP[((size_t)n*1024 + t)*4];
    const int4 v1 = *(const int4*)&SP[((size_t)n*1024 + t + 512)*4];
    if (t < 80) stbl[t] = STBL[t];

    // S-row prefetch (T14) — in flight together with the gathers below.
    u32 pre0[8], pre1[8];
    {
        const u16* sr0 = S + (((size_t)w << 10) + n) * 1024;
        const u16* sr1 = S + (((size_t)(w + 8) << 10) + n) * 1024;
        #pragma unroll
        for (int j = 0; j < 8; ++j) pre0[j] = *(const u32*)&sr0[lane*2 + j*128];
        #pragma unroll
        for (int j = 0; j < 8; ++j) pre1[j] = *(const u32*)&sr1[lane*2 + j*128];
    }
    // issue ALL 16 C-gathers now (4 per k per chunk)
    u16x8 g1[2][4], g2[2][4];
    #pragma unroll
    for (int k = 0; k < 2; ++k) {
        int4 e4 = k ? v1 : v0;
        g1[k][0] = *(const u16x8*)&C[(size_t)e4.x*64 +  0];
        g1[k][1] = *(const u16x8*)&C[(size_t)e4.y*64 + 16];
        g1[k][2] = *(const u16x8*)&C[(size_t)e4.z*64 + 32];
        g1[k][3] = *(const u16x8*)&C[(size_t)e4.w*64 + 48];
        g2[k][0] = *(const u16x8*)&C[(size_t)e4.x*64 +  0 + 8];
        g2[k][1] = *(const u16x8*)&C[(size_t)e4.y*64 + 16 + 8];
        g2[k][2] = *(const u16x8*)&C[(size_t)e4.z*64 + 32 + 8];
        g2[k][3] = *(const u16x8*)&C[(size_t)e4.w*64 + 48 + 8];
    }
    __syncthreads();

    // ---- chunk 1 (heads 0..7) ----
    #pragma unroll
    for (int k = 0; k < 2; ++k) {
        int m   = t + k*512;
        int sdv = sdl[m];
        int cl  = sdv > 4 ? 4 : (sdv < 0 ? 0 : sdv);
        float4 b0 = *(const float4*)&stbl[cl*16];
        float4 b1 = *(const float4*)&stbl[cl*16 + 4];
        bias[0][m] = b0.x + bf2f(g1[k][0][0]) + bf2f(g1[k][1][0]) + bf2f(g1[k][2][0]) + bf2f(g1[k][3][0]);
        bias[1][m] = b0.y + bf2f(g1[k][0][1]) + bf2f(g1[k][1][1]) + bf2f(g1[k][2][1]) + bf2f(g1[k][3][1]);
        bias[2][m] = b0.z + bf2f(g1[k][0][2]) + bf2f(g1[k][1][2]) + bf2f(g1[k][2][2]) + bf2f(g1[k][3][2]);
        bias[3][m] = b0.w + bf2f(g1[k][0][3]) + bf2f(g1[k][1][3]) + bf2f(g1[k][2][3]) + bf2f(g1[k][3][3]);
        bias[4][m] = b1.x + bf2f(g1[k][0][4]) + bf2f(g1[k][1][4]) + bf2f(g1[k][2][4]) + bf2f(g1[k][3][4]);
        bias[5][m] = b1.y + bf2f(g1[k][0][5]) + bf2f(g1[k][1][5]) + bf2f(g1[k][2][5]) + bf2f(g1[k][3][5]);
        bias[6][m] = b1.z + bf2f(g1[k][0][6]) + bf2f(g1[k][1][6]) + bf2f(g1[k][2][6]) + bf2f(g1[k][3][6]);
        bias[7][m] = b1.w + bf2f(g1[k][0][7]) + bf2f(g1[k][1][7]) + bf2f(g1[k][2][7]) + bf2f(g1[k][3][7]);
    }
    __syncthreads();
    #pragma unroll
    for (int hc = 0; hc < 16; hc += 8) {
        if (hc) {
            // ---- chunk 2 bias (heads 8..15) from parked registers ----
            __syncthreads();
            #pragma unroll
            for (int k = 0; k < 2; ++k) {
                int m   = t + k*512;
                int sdv = sdl[m];
                int cl  = sdv > 4 ? 4 : (sdv < 0 ? 0 : sdv);
                float4 b0 = *(const float4*)&stbl[cl*16 + 8];
                float4 b1 = *(const float4*)&stbl[cl*16 + 12];
                bias[0][m] = b0.x + bf2f(g2[k][0][0]) + bf2f(g2[k][1][0]) + bf2f(g2[k][2][0]) + bf2f(g2[k][3][0]);
                bias[1][m] = b0.y + bf2f(g2[k][0][1]) + bf2f(g2[k][1][1]) + bf2f(g2[k][2][1]) + bf2f(g2[k][3][1]);
                bias[2][m] = b0.z + bf2f(g2[k][0][2]) + bf2f(g2[k][1][2]) + bf2f(g2[k][2][2]) + bf2f(g2[k][3][2]);
                bias[3][m] = b0.w + bf2f(g2[k][0][3]) + bf2f(g2[k][1][3]) + bf2f(g2[k][2][3]) + bf2f(g2[k][3][3]);
                bias[4][m] = b1.x + bf2f(g2[k][0][4]) + bf2f(g2[k][1][4]) + bf2f(g2[k][2][4]) + bf2f(g2[k][3][4]);
                bias[5][m] = b1.y + bf2f(g2[k][0][5]) + bf2f(g2[k][1][5]) + bf2f(g2[k][2][5]) + bf2f(g2[k][3][5]);
                bias[6][m] = b1.z + bf2f(g2[k][0][6]) + bf2f(g2[k][1][6]) + bf2f(g2[k][2][6]) + bf2f(g2[k][3][6]);
                bias[7][m] = b1.w + bf2f(g2[k][0][7]) + bf2f(g2[k][1][7]) + bf2f(g2[k][2][7]) + bf2f(g2[k][3][7]);
            }
            __syncthreads();
        }
        const int h = hc + w;
        u16* srow = S + (((size_t)h << 10) + n) * 1024;
        float v[16];
        float lmax = -INFINITY;
        #pragma unroll
        for (int j = 0; j < 8; ++j) {
            int m = lane*2 + j*128;
            u32 pk = hc ? pre1[j] : pre0[j];
            float2 bb = *(const float2*)&bias[w][m];
            int2 sd2 = *(const int2*)&sdl[m];
            float x0 = (sd2.x <= 0) ? -INFINITY : h2f((u16)(pk & 0xffffu)) + bb.x;
            float x1 = (sd2.y <= 0) ? -INFINITY : h2f((u16)(pk >> 16)) + bb.y;
            v[2*j] = x0; v[2*j+1] = x1;
            lmax = fmaxf(lmax, fmaxf(x0, x1));
        }
        #pragma unroll
        for (int o = 32; o; o >>= 1) lmax = fmaxf(lmax, __shfl_xor(lmax, o));
        float lsum = 0.f;
        #pragma unroll
        for (int j = 0; j < 16; ++j) { v[j] = __expf(v[j] - lmax); lsum += v[j]; }
        #pragma unroll
        for (int o = 32; o; o >>= 1) lsum += __shfl_xor(lsum, o);
        float inv = 1.f / lsum;
        #pragma unroll
        for (int j = 0; j < 8; ++j) {
            int m = lane*2 + j*128;
            u32 pk = ((u32)f2bf(v[2*j+1] * inv) << 16) | f2bf(v[2*j] * inv);
            *(u32*)&srow[m] = pk;
        }
    }
}

// ---------------------------------------------------------------
extern "C" void kernel_launch(void* const* d_in, const int* in_sizes, int n_in,
                              void* d_out, int out_size, void* d_ws, size_t ws_size,
                              hipStream_t stream)
{
    const float* node_feat = (const float*)d_in[0];
    const float* edge_feat = (const float*)d_in[1];
    const int*   sd        = (const int*)d_in[3];
    const int*   sp        = (const int*)d_in[4];
    const float* Wq = (const float*)d_in[6];
    const float* bq = (const float*)d_in[7];
    const float* Wk = (const float*)d_in[8];
    const float* bk = (const float*)d_in[9];
    const float* Wv = (const float*)d_in[10];
    const float* bv = (const float*)d_in[11];
    const float* Wo = (const float*)d_in[12];
    const float* bo = (const float*)d_in[13];
    const float* spatial = (const float*)d_in[14];
    const float* ew      = (const float*)d_in[15];
    float* out = (float*)d_out;

    char* base = (char*)d_ws;
    u16*   Xb = (u16*)(base);                           // 2MB (later Vt)
    u16*   Qb = (u16*)(base + ((size_t)2 << 20));       // 2MB (later attnout)
    u16*   Kb = (u16*)(base + ((size_t)4 << 20));       // 2MB
    u16*   Vb = (u16*)(base + ((size_t)6 << 20));       // 2MB
    u16*   Wt = (u16*)(base + ((size_t)8 << 20));       // 8MB
    u16*   C  = (u16*)(base + ((size_t)16 << 20));      // 2,097,280 B (bf16)
    u16*   S  = (u16*)(base + ((size_t)19 << 20));      // 32MB fp16
    u16*   Vt = Xb;   // alias: Xb dead after qkv_gemm
    u16*   AO = Qb;   // alias: Qb dead after qk_gemm

    conv_x<<<512, 256, 0, stream>>>(node_feat, Xb);
    conv_wt<<<dim3(16,16,4), 256, 0, stream>>>(Wq, Wk, Wv, Wo, Wt);
    edge_pre_kernel<<<dim3(E_/16 + 1), 256, 0, stream>>>(edge_feat, ew, C);
    qkv_gemm<<<dim3(24,16), 256, 0, stream>>>(Xb, Wt, bq, bk, bv, Qb, Kb, Vb);
    transpose_v<<<dim3(16,16), 256, 0, stream>>>(Vb, Vt);
    qk_gemm<<<dim3(8,8,16), 256, 0, stream>>>(Qb, Kb, S);
    bias_softmax8<<<dim3(1024), 512, 0, stream>>>(sd, sp, C, spatial, S);
    pv_gemm<<<dim3(16,16), 256, 0, stream>>>(S, Vt, AO);
    out_gemm<<<dim3(16,16), 256, 0, stream>>>(AO, Wt + (size_t)3*1024*1024, bo, out);
}